// Round 1
// baseline (367.720 us; speedup 1.0000x reference)
//
#include <hip/hip_runtime.h>

#define NROWS 12288
#define BSZ   4096
#define DIM   128

typedef __bf16 bf16x8 __attribute__((ext_vector_type(8)));
typedef float  f32x4  __attribute__((ext_vector_type(4)));

__device__ __forceinline__ unsigned short f2bf(float f) {
  unsigned int u = __float_as_uint(f);
  u = u + 0x7FFFu + ((u >> 16) & 1u);   // round-to-nearest-even
  return (unsigned short)(u >> 16);
}
__device__ __forceinline__ float bf2f(unsigned short h) {
  return __uint_as_float(((unsigned int)h) << 16);
}

// ---------------------------------------------------------------------------
// Kernel 1: build bf16 emb copy, sq[i] = ||emb_i||^2 (of the ROUNDED values,
// so d2 is a true metric >= 0 up to fp32 accum), reg partial sums, init negmin.
// One wave per row; 3072 blocks x 256 threads.
// ---------------------------------------------------------------------------
__global__ void prep_k(const float* __restrict__ a, const float* __restrict__ p,
                       const float* __restrict__ nn,
                       unsigned short* __restrict__ embh, float* __restrict__ sq,
                       unsigned int* __restrict__ negbits, float* __restrict__ regsum) {
  const int w = threadIdx.x >> 6, lane = threadIdx.x & 63;
  const int row = blockIdx.x * 4 + w;
  const float* src = (row < BSZ)     ? a  + (size_t)row * DIM
                   : (row < 2 * BSZ) ? p  + (size_t)(row - BSZ) * DIM
                                     : nn + (size_t)(row - 2 * BSZ) * DIM;
  const float2 x = reinterpret_cast<const float2*>(src)[lane];
  const unsigned short h0 = f2bf(x.x), h1 = f2bf(x.y);
  reinterpret_cast<ushort2*>(embh + (size_t)row * DIM)[lane] = make_ushort2(h0, h1);
  const float rx = bf2f(h0), ry = bf2f(h1);
  float s = rx * rx + ry * ry;                       // sq of rounded values
  const float ax = fabsf(x.x) - 1.0f, ay = fabsf(x.y) - 1.0f;
  float rg = ax * ax + ay * ay;                      // reg from exact values
  for (int m = 32; m; m >>= 1) { s += __shfl_xor(s, m); rg += __shfl_xor(rg, m); }
  if (lane == 0) {
    sq[row] = s;
    negbits[row] = 0x7F800000u;                      // +inf bits
    atomicAdd(regsum, rg);
  }
}

// ---------------------------------------------------------------------------
// Kernel 2: pos_max^2 per row, exact fp32 (only 3 same-label distances/row).
// One wave per triplet index; 1024 blocks x 256 threads.
// ---------------------------------------------------------------------------
__global__ void posmax_k(const float* __restrict__ a, const float* __restrict__ p,
                         const float* __restrict__ nn, float* __restrict__ posmax2) {
  const int w = threadIdx.x >> 6, lane = threadIdx.x & 63;
  const int i = blockIdx.x * 4 + w;
  const float2 av = reinterpret_cast<const float2*>(a  + (size_t)i * DIM)[lane];
  const float2 pv = reinterpret_cast<const float2*>(p  + (size_t)i * DIM)[lane];
  const float2 nv = reinterpret_cast<const float2*>(nn + (size_t)i * DIM)[lane];
  float dx, dy, dap, dan, dpn;
  dx = av.x - pv.x; dy = av.y - pv.y; dap = dx * dx + dy * dy;
  dx = av.x - nv.x; dy = av.y - nv.y; dan = dx * dx + dy * dy;
  dx = pv.x - nv.x; dy = pv.y - nv.y; dpn = dx * dx + dy * dy;
  for (int m = 32; m; m >>= 1) {
    dap += __shfl_xor(dap, m); dan += __shfl_xor(dan, m); dpn += __shfl_xor(dpn, m);
  }
  if (lane == 0) {
    posmax2[i]           = fmaxf(dap, dan);   // row in a-panel
    posmax2[BSZ + i]     = fmaxf(dap, dpn);   // row in p-panel
    posmax2[2 * BSZ + i] = fmaxf(dan, dpn);   // row in n-panel
  }
}

// ---------------------------------------------------------------------------
// Kernel 3: neg_min^2. Fused GEMM (E*E^T, bf16 MFMA 16x16x32) + row-min.
// Block = 128 rows x 1536 cols; A-tile (128x128) fully in registers (128 VGPR);
// 4 waves partition columns into private 16-col strips -> NO barriers,
// per-wave double-buffered 4KB LDS strips. Grid (96, 8).
// ---------------------------------------------------------------------------
__global__ __launch_bounds__(256, 2) void negmin_k(
    const unsigned short* __restrict__ embh,
    const float* __restrict__ sq,
    unsigned int* __restrict__ negbits) {
  __shared__ bf16x8 ldsB[2][4][256];   // [buf][wave][unit16B] = 32 KB
  const int tid = threadIdx.x;
  const int w    = tid >> 6;
  const int lane = tid & 63;
  const int c16  = lane & 15;          // col-within-strip / A-row-within-tile
  const int q    = lane >> 4;          // k-quad
  const int rowBase  = blockIdx.x * 128;
  const int colBase0 = blockIdx.y * 1536;

  // A fragments: rows [rowBase, rowBase+128), all K=128. 8 mtiles x 4 ksteps.
  // A[m=lane&15][k=q*8+j] for 16x16x32.
  bf16x8 afrag[8][4];
  {
    const char* abase = (const char*)embh + (size_t)(rowBase + c16) * 256 + q * 16;
#pragma unroll
    for (int mt = 0; mt < 8; ++mt)
#pragma unroll
      for (int ks = 0; ks < 4; ++ks)
        afrag[mt][ks] = *reinterpret_cast<const bf16x8*>(abase + mt * (16 * 256) + ks * 64);
  }

  float minv[8][4];
#pragma unroll
  for (int mt = 0; mt < 8; ++mt)
#pragma unroll
    for (int r = 0; r < 4; ++r) minv[mt][r] = __builtin_inff();

  uint4 stg[4];
  const char* gqoff = (const char*)embh + q * 16;
  auto load_strip = [&](int c) {
    const int colStart = colBase0 + c * 64 + w * 16;
    const char* gp = gqoff + (size_t)(colStart + c16) * 256;
#pragma unroll
    for (int pp = 0; pp < 4; ++pp)
      stg[pp] = *reinterpret_cast<const uint4*>(gp + pp * 64);
  };
  auto store_strip = [&](int buf) {
#pragma unroll
    for (int pp = 0; pp < 4; ++pp) {
      union { uint4 u; bf16x8 v; } cv;
      cv.u = stg[pp];
      ldsB[buf][w][pp * 64 + lane] = cv.v;   // lane-consecutive 16B: conflict-free
    }
  };

  load_strip(0);
  store_strip(0);

  for (int c = 0; c < 24; ++c) {
    const int buf = c & 1;
    if (c + 1 < 24) load_strip(c + 1);        // prefetch next strip to regs
    const int colStart = colBase0 + c * 64 + w * 16;
    const float sqb = sq[colStart + c16];

    f32x4 acc[8] = {};
#pragma unroll
    for (int ks = 0; ks < 4; ++ks) {
      const bf16x8 bfrag = ldsB[buf][w][ks * 64 + lane];  // B[k=q*8+j][n=lane&15]
#pragma unroll
      for (int mt = 0; mt < 8; ++mt)
        acc[mt] = __builtin_amdgcn_mfma_f32_16x16x32_bf16(afrag[mt][ks], bfrag, acc[mt], 0, 0, 0);
    }
    if (c + 1 < 24) store_strip((c + 1) & 1); // fill other buffer for next iter

    // Epilogue: track min over j of (sq_j - 2*dot). sq_i added at the end.
    // Exclusion (j == i mod 4096) only possible when dd in [0,128) U (4080,4096).
    const int dd = (colStart - rowBase) & 4095;
    if (dd < 128 || dd > 4080) {
      const int lv = dd + c16 - q * 4;
#pragma unroll
      for (int mt = 0; mt < 8; ++mt)
#pragma unroll
        for (int r = 0; r < 4; ++r) {
          float v = fmaf(-2.f, acc[mt][r], sqb);
          const int K = mt * 16 + r;
          if (lv == K || lv == K + 4096) v = __builtin_inff();
          minv[mt][r] = fminf(minv[mt][r], v);
        }
    } else {
#pragma unroll
      for (int mt = 0; mt < 8; ++mt)
#pragma unroll
        for (int r = 0; r < 4; ++r)
          minv[mt][r] = fminf(minv[mt][r], fmaf(-2.f, acc[mt][r], sqb));
    }
  }

  // Reduce over the 16 column-lanes sharing each row, then atomicMin (uint
  // bits are order-preserving for floats >= 0).
#pragma unroll
  for (int mt = 0; mt < 8; ++mt)
#pragma unroll
    for (int r = 0; r < 4; ++r) {
      float v = minv[mt][r];
      v = fminf(v, __shfl_xor(v, 1));
      v = fminf(v, __shfl_xor(v, 2));
      v = fminf(v, __shfl_xor(v, 4));
      v = fminf(v, __shfl_xor(v, 8));
      if (c16 == 0) {
        const int row = rowBase + mt * 16 + q * 4 + r;  // C/D: row=(lane>>4)*4+r
        float d2 = sq[row] + v;
        d2 = fmaxf(d2, 0.f);
        atomicMin(&negbits[row], __float_as_uint(d2));
      }
    }
}

// ---------------------------------------------------------------------------
// Kernel 4: final scalar. loss = mean(relu(sqrt(pos2)-sqrt(neg2)+margin)) +
// alpha * regsum / (3*B*D). Single block.
// ---------------------------------------------------------------------------
__global__ void final_k(const float* __restrict__ posmax2,
                        const unsigned int* __restrict__ negbits,
                        const float* __restrict__ regsum, float* __restrict__ out) {
  __shared__ float red[4];
  const int tid = threadIdx.x;  // 256
  float s = 0.f;
  for (int i = tid; i < NROWS; i += 256) {
    const float pm = sqrtf(posmax2[i]);
    const float nm = sqrtf(__uint_as_float(negbits[i]));
    s += fmaxf(pm - nm + 0.4f, 0.f);
  }
  for (int m = 32; m; m >>= 1) s += __shfl_xor(s, m);
  if ((tid & 63) == 0) red[tid >> 6] = s;
  __syncthreads();
  if (tid == 0) {
    const float t = red[0] + red[1] + red[2] + red[3];
    out[0] = t / (float)NROWS + 0.01f * (regsum[0] / (float)(NROWS * DIM));
  }
}

// ---------------------------------------------------------------------------
extern "C" void kernel_launch(void* const* d_in, const int* in_sizes, int n_in,
                              void* d_out, int out_size, void* d_ws, size_t ws_size,
                              hipStream_t stream) {
  const float* a  = (const float*)d_in[0];
  const float* p  = (const float*)d_in[1];
  const float* nn = (const float*)d_in[2];
  float* out = (float*)d_out;
  char* ws = (char*)d_ws;

  const size_t EMBH_BYTES = (size_t)NROWS * DIM * 2;       // 3,145,728
  unsigned short* embh   = (unsigned short*)ws;
  float*          sq     = (float*)(ws + EMBH_BYTES);
  unsigned int*   negbit = (unsigned int*)(ws + EMBH_BYTES + (size_t)NROWS * 4);
  float*          pos2   = (float*)(ws + EMBH_BYTES + (size_t)NROWS * 8);
  float*          regsum = (float*)(ws + EMBH_BYTES + (size_t)NROWS * 12);

  hipMemsetAsync(regsum, 0, sizeof(float), stream);
  prep_k<<<NROWS / 4, 256, 0, stream>>>(a, p, nn, embh, sq, negbit, regsum);
  posmax_k<<<BSZ / 4, 256, 0, stream>>>(a, p, nn, pos2);
  negmin_k<<<dim3(96, 8), 256, 0, stream>>>(embh, sq, negbit);
  final_k<<<1, 256, 0, stream>>>(pos2, negbit, regsum, out);
}

// Round 2
// 213.109 us; speedup vs baseline: 1.7255x; 1.7255x over previous
//
#include <hip/hip_runtime.h>

#define NROWS 12288
#define BSZ   4096
#define DIM   128

typedef __bf16 bf16x8 __attribute__((ext_vector_type(8)));
typedef float  f32x4  __attribute__((ext_vector_type(4)));

__device__ __forceinline__ unsigned short f2bf(float f) {
  unsigned int u = __float_as_uint(f);
  u = u + 0x7FFFu + ((u >> 16) & 1u);   // round-to-nearest-even
  return (unsigned short)(u >> 16);
}
__device__ __forceinline__ float bf2f(unsigned short h) {
  return __uint_as_float(((unsigned int)h) << 16);
}

// ---------------------------------------------------------------------------
// Kernel 1 (fused prep + posmax): one wave per triplet index i.
// Reads a_i, p_i, n_i once; emits bf16 rows for all 3 panels, sq of rounded
// values, exact-fp32 pos_max^2 for all 3 rows, per-index reg partial (NO
// atomics — round 1 showed a single-address atomicAdd serializing 158 us),
// and inits negbits. Grid 1024 x 256.
// ---------------------------------------------------------------------------
__global__ void prep_k(const float* __restrict__ a, const float* __restrict__ p,
                       const float* __restrict__ nn,
                       unsigned short* __restrict__ embh, float* __restrict__ sq,
                       unsigned int* __restrict__ negbits,
                       float* __restrict__ posmax2, float* __restrict__ regpart) {
  const int w = threadIdx.x >> 6, lane = threadIdx.x & 63;
  const int i = blockIdx.x * 4 + w;
  const float2 av = reinterpret_cast<const float2*>(a  + (size_t)i * DIM)[lane];
  const float2 pv = reinterpret_cast<const float2*>(p  + (size_t)i * DIM)[lane];
  const float2 nv = reinterpret_cast<const float2*>(nn + (size_t)i * DIM)[lane];

  const unsigned short ha0 = f2bf(av.x), ha1 = f2bf(av.y);
  const unsigned short hp0 = f2bf(pv.x), hp1 = f2bf(pv.y);
  const unsigned short hn0 = f2bf(nv.x), hn1 = f2bf(nv.y);
  reinterpret_cast<ushort2*>(embh + (size_t)i * DIM)[lane]             = make_ushort2(ha0, ha1);
  reinterpret_cast<ushort2*>(embh + (size_t)(BSZ + i) * DIM)[lane]     = make_ushort2(hp0, hp1);
  reinterpret_cast<ushort2*>(embh + (size_t)(2 * BSZ + i) * DIM)[lane] = make_ushort2(hn0, hn1);

  // sq of ROUNDED values (so the GEMM-based d2 is consistent & >= 0)
  float rax = bf2f(ha0), ray = bf2f(ha1);
  float rpx = bf2f(hp0), rpy = bf2f(hp1);
  float rnx = bf2f(hn0), rny = bf2f(hn1);
  float sa = rax * rax + ray * ray;
  float sp = rpx * rpx + rpy * rpy;
  float sn = rnx * rnx + rny * rny;

  // reg from exact values
  float t0 = fabsf(av.x) - 1.f, t1 = fabsf(av.y) - 1.f;
  float t2 = fabsf(pv.x) - 1.f, t3 = fabsf(pv.y) - 1.f;
  float t4 = fabsf(nv.x) - 1.f, t5 = fabsf(nv.y) - 1.f;
  float rg = t0 * t0 + t1 * t1 + t2 * t2 + t3 * t3 + t4 * t4 + t5 * t5;

  // pos distances, exact fp32
  float dx, dy;
  dx = av.x - pv.x; dy = av.y - pv.y; float dap = dx * dx + dy * dy;
  dx = av.x - nv.x; dy = av.y - nv.y; float dan = dx * dx + dy * dy;
  dx = pv.x - nv.x; dy = pv.y - nv.y; float dpn = dx * dx + dy * dy;

  for (int m = 32; m; m >>= 1) {
    sa  += __shfl_xor(sa, m);  sp  += __shfl_xor(sp, m);  sn  += __shfl_xor(sn, m);
    rg  += __shfl_xor(rg, m);
    dap += __shfl_xor(dap, m); dan += __shfl_xor(dan, m); dpn += __shfl_xor(dpn, m);
  }
  if (lane == 0) {
    sq[i] = sa; sq[BSZ + i] = sp; sq[2 * BSZ + i] = sn;
    negbits[i] = negbits[BSZ + i] = negbits[2 * BSZ + i] = 0x7F800000u;  // +inf
    posmax2[i]           = fmaxf(dap, dan);
    posmax2[BSZ + i]     = fmaxf(dap, dpn);
    posmax2[2 * BSZ + i] = fmaxf(dan, dpn);
    regpart[i] = rg;
  }
}

// ---------------------------------------------------------------------------
// Kernel 2: neg_min^2. Fused GEMM (E*E^T, bf16 MFMA 16x16x32) + row-min.
// Block = 128 rows x 1536 cols; A-tile (128x128) fully in registers (128 VGPR);
// 4 waves partition columns into private 16-col strips -> NO barriers,
// per-wave double-buffered 4KB LDS strips. Grid (96, 8).
// ---------------------------------------------------------------------------
__global__ __launch_bounds__(256, 2) void negmin_k(
    const unsigned short* __restrict__ embh,
    const float* __restrict__ sq,
    unsigned int* __restrict__ negbits) {
  __shared__ bf16x8 ldsB[2][4][256];   // [buf][wave][unit16B] = 32 KB
  const int tid = threadIdx.x;
  const int w    = tid >> 6;
  const int lane = tid & 63;
  const int c16  = lane & 15;          // col-within-strip / A-row-within-tile
  const int q    = lane >> 4;          // k-quad
  const int rowBase  = blockIdx.x * 128;
  const int colBase0 = blockIdx.y * 1536;

  // A fragments: rows [rowBase, rowBase+128), all K=128. 8 mtiles x 4 ksteps.
  // A[m=lane&15][k=q*8+j] for 16x16x32.
  bf16x8 afrag[8][4];
  {
    const char* abase = (const char*)embh + (size_t)(rowBase + c16) * 256 + q * 16;
#pragma unroll
    for (int mt = 0; mt < 8; ++mt)
#pragma unroll
      for (int ks = 0; ks < 4; ++ks)
        afrag[mt][ks] = *reinterpret_cast<const bf16x8*>(abase + mt * (16 * 256) + ks * 64);
  }

  float minv[8][4];
#pragma unroll
  for (int mt = 0; mt < 8; ++mt)
#pragma unroll
    for (int r = 0; r < 4; ++r) minv[mt][r] = __builtin_inff();

  uint4 stg[4];
  const char* gqoff = (const char*)embh + q * 16;
  auto load_strip = [&](int c) {
    const int colStart = colBase0 + c * 64 + w * 16;
    const char* gp = gqoff + (size_t)(colStart + c16) * 256;
#pragma unroll
    for (int pp = 0; pp < 4; ++pp)
      stg[pp] = *reinterpret_cast<const uint4*>(gp + pp * 64);
  };
  auto store_strip = [&](int buf) {
#pragma unroll
    for (int pp = 0; pp < 4; ++pp) {
      union { uint4 u; bf16x8 v; } cv;
      cv.u = stg[pp];
      ldsB[buf][w][pp * 64 + lane] = cv.v;   // lane-consecutive 16B: conflict-free
    }
  };

  load_strip(0);
  store_strip(0);

  for (int c = 0; c < 24; ++c) {
    const int buf = c & 1;
    if (c + 1 < 24) load_strip(c + 1);        // prefetch next strip to regs
    const int colStart = colBase0 + c * 64 + w * 16;
    const float sqb = sq[colStart + c16];

    f32x4 acc[8] = {};
#pragma unroll
    for (int ks = 0; ks < 4; ++ks) {
      const bf16x8 bfrag = ldsB[buf][w][ks * 64 + lane];  // B[k=q*8+j][n=lane&15]
#pragma unroll
      for (int mt = 0; mt < 8; ++mt)
        acc[mt] = __builtin_amdgcn_mfma_f32_16x16x32_bf16(afrag[mt][ks], bfrag, acc[mt], 0, 0, 0);
    }
    if (c + 1 < 24) store_strip((c + 1) & 1); // fill other buffer for next iter

    // Epilogue: track min over j of (sq_j - 2*dot). sq_i added at the end.
    // Exclusion (j == i mod 4096) only possible when dd in [0,128) U (4080,4096).
    const int dd = (colStart - rowBase) & 4095;
    if (dd < 128 || dd > 4080) {
      const int lv = dd + c16 - q * 4;
#pragma unroll
      for (int mt = 0; mt < 8; ++mt)
#pragma unroll
        for (int r = 0; r < 4; ++r) {
          float v = fmaf(-2.f, acc[mt][r], sqb);
          const int K = mt * 16 + r;
          if (lv == K || lv == K + 4096) v = __builtin_inff();
          minv[mt][r] = fminf(minv[mt][r], v);
        }
    } else {
#pragma unroll
      for (int mt = 0; mt < 8; ++mt)
#pragma unroll
        for (int r = 0; r < 4; ++r)
          minv[mt][r] = fminf(minv[mt][r], fmaf(-2.f, acc[mt][r], sqb));
    }
  }

  // Reduce over the 16 column-lanes sharing each row, then atomicMin (uint
  // bits are order-preserving for floats >= 0). 8 atomics per row, distinct
  // addresses per row -> no contention hotspot.
#pragma unroll
  for (int mt = 0; mt < 8; ++mt)
#pragma unroll
    for (int r = 0; r < 4; ++r) {
      float v = minv[mt][r];
      v = fminf(v, __shfl_xor(v, 1));
      v = fminf(v, __shfl_xor(v, 2));
      v = fminf(v, __shfl_xor(v, 4));
      v = fminf(v, __shfl_xor(v, 8));
      if (c16 == 0) {
        const int row = rowBase + mt * 16 + q * 4 + r;  // C/D: row=(lane>>4)*4+r
        float d2 = sq[row] + v;
        d2 = fmaxf(d2, 0.f);
        atomicMin(&negbits[row], __float_as_uint(d2));
      }
    }
}

// ---------------------------------------------------------------------------
// Kernel 3: final scalar. loss = mean(relu(sqrt(pos2)-sqrt(neg2)+margin)) +
// alpha * sum(regpart) / (3*B*D). Single block.
// ---------------------------------------------------------------------------
__global__ void final_k(const float* __restrict__ posmax2,
                        const unsigned int* __restrict__ negbits,
                        const float* __restrict__ regpart, float* __restrict__ out) {
  __shared__ float red[4], redr[4];
  const int tid = threadIdx.x;  // 256
  float s = 0.f;
  for (int i = tid; i < NROWS; i += 256) {
    const float pm = sqrtf(posmax2[i]);
    const float nm = sqrtf(__uint_as_float(negbits[i]));
    s += fmaxf(pm - nm + 0.4f, 0.f);
  }
  float rg = 0.f;
  for (int i = tid; i < BSZ; i += 256) rg += regpart[i];
  for (int m = 32; m; m >>= 1) { s += __shfl_xor(s, m); rg += __shfl_xor(rg, m); }
  if ((tid & 63) == 0) { red[tid >> 6] = s; redr[tid >> 6] = rg; }
  __syncthreads();
  if (tid == 0) {
    const float t  = red[0] + red[1] + red[2] + red[3];
    const float tr = redr[0] + redr[1] + redr[2] + redr[3];
    out[0] = t / (float)NROWS + 0.01f * (tr / (float)(NROWS * DIM));
  }
}

// ---------------------------------------------------------------------------
extern "C" void kernel_launch(void* const* d_in, const int* in_sizes, int n_in,
                              void* d_out, int out_size, void* d_ws, size_t ws_size,
                              hipStream_t stream) {
  const float* a  = (const float*)d_in[0];
  const float* p  = (const float*)d_in[1];
  const float* nn = (const float*)d_in[2];
  float* out = (float*)d_out;
  char* ws = (char*)d_ws;

  const size_t EMBH_BYTES = (size_t)NROWS * DIM * 2;       // 3,145,728
  unsigned short* embh    = (unsigned short*)ws;
  float*          sq      = (float*)(ws + EMBH_BYTES);
  unsigned int*   negbit  = (unsigned int*)(ws + EMBH_BYTES + (size_t)NROWS * 4);
  float*          pos2    = (float*)(ws + EMBH_BYTES + (size_t)NROWS * 8);
  float*          regpart = (float*)(ws + EMBH_BYTES + (size_t)NROWS * 12);

  prep_k<<<BSZ / 4, 256, 0, stream>>>(a, p, nn, embh, sq, negbit, pos2, regpart);
  negmin_k<<<dim3(96, 8), 256, 0, stream>>>(embh, sq, negbit);
  final_k<<<1, 256, 0, stream>>>(pos2, negbit, regpart, out);
}